// Round 10
// baseline (2540.373 us; speedup 1.0000x reference)
//
#include <hip/hip_runtime.h>
#include <math.h>

#define N_NODES 50000
#define M_EDGES 800000
#define INP 256
#define KCAP 8
#define FAC 12
#define KF 96            // K*FAC
#define ROUTIT 6
#define DMAX 24          // register-cached edges per node (6 slots x 4 subgroups)

// NOTE: clang's AMDGPU builtins use __fp16 vectors (BuiltinsAMDGPU.def: cvt_pkrtz
// = "V2hff", fdot2 = "fV2hV2hfb"). _Float16 vectors are a DIFFERENT type and fail
// to compile (round-8 lesson). Use __fp16 throughout.
typedef __fp16 h2 __attribute__((ext_vector_type(2)));

#if __has_builtin(__builtin_amdgcn_fdot2)
#define FDOT2(a, b, c) __builtin_amdgcn_fdot2((a), (b), (c), false)
#else
#define FDOT2(a, b, c) (fmaf((float)(a)[1], (float)(b)[1], fmaf((float)(a)[0], (float)(b)[0], (c))))
#endif

// ---------------- ws layout (bytes) ----------------
#define OFF_ZA      0u
#define OFF_ZB      19200000u
#define OFF_ROWPTR  38400000u   // 50001 ints (padded)
#define OFF_PARTIAL 38600016u   // 50000 ints
#define OFF_CURSOR  38800016u   // 50000 ints (counts -> row starts)
#define OFF_BSUMS   39000016u   // 256 ints
#define OFF_CSR     39001040u   // 800000 ints
#define OFF_WT      42201040u   // 256*96 floats

// ---------- W transpose: Wt[i][kf] = W[k][i][f]  (i-major, kf-minor) ----------
__global__ void wt_transpose(const float* __restrict__ W, float* __restrict__ Wt) {
    int idx = blockIdx.x * 256 + threadIdx.x;
    if (idx >= INP * KF) return;
    int i = idx / KF, kf = idx % KF;
    int k = kf / FAC, f = kf % FAC;
    Wt[i * KF + kf] = W[(k * INP + i) * FAC + f];
}

// ---------- init: zA[n][kf] = l2norm_percap(relu(X[n,:].Wt[:,kf] + b[kf])) ----------
// thread = 4 nodes x 24 kf (2 FULL capsules) -> X row multiplier 24 -> 4 (1.23GB -> 205MB)
// and per-capsule l2norm fuses in-thread (prep_norm kernel deleted).
__global__ __launch_bounds__(256, 2) void init_proj(const float* __restrict__ X,
                                                    const float* __restrict__ Wt,
                                                    const float* __restrict__ b,
                                                    float* __restrict__ zA) {
    int gid    = blockIdx.x * 256 + threadIdx.x;
    int quad   = gid >> 2;      // node quad id
    int pairId = gid & 3;       // capsule pair (2 capsules = 24 kf)
    if (quad >= N_NODES / 4) return;
    int nb  = quad * 4;
    int kf0 = pairId * 24;

    float acc[4][24];
    #pragma unroll
    for (int m = 0; m < 4; ++m)
        #pragma unroll
        for (int q = 0; q < 24; ++q) acc[m][q] = 0.f;

    const float4* X4 = (const float4*)X;

    for (int i4 = 0; i4 < INP / 4; ++i4) {
        float4 xv[4];
        #pragma unroll
        for (int m = 0; m < 4; ++m)
            xv[m] = X4[(size_t)(nb + m) * (INP / 4) + i4];

        #pragma unroll
        for (int r = 0; r < 4; ++r) {
            const float4* wr = (const float4*)(Wt + (size_t)(i4 * 4 + r) * KF + kf0);
            float4 w0 = wr[0], w1 = wr[1], w2 = wr[2], w3 = wr[3], w4 = wr[4], w5 = wr[5];
            #pragma unroll
            for (int m = 0; m < 4; ++m) {
                float xs = (r == 0) ? xv[m].x : (r == 1) ? xv[m].y : (r == 2) ? xv[m].z : xv[m].w;
                acc[m][0]  = fmaf(xs, w0.x, acc[m][0]);
                acc[m][1]  = fmaf(xs, w0.y, acc[m][1]);
                acc[m][2]  = fmaf(xs, w0.z, acc[m][2]);
                acc[m][3]  = fmaf(xs, w0.w, acc[m][3]);
                acc[m][4]  = fmaf(xs, w1.x, acc[m][4]);
                acc[m][5]  = fmaf(xs, w1.y, acc[m][5]);
                acc[m][6]  = fmaf(xs, w1.z, acc[m][6]);
                acc[m][7]  = fmaf(xs, w1.w, acc[m][7]);
                acc[m][8]  = fmaf(xs, w2.x, acc[m][8]);
                acc[m][9]  = fmaf(xs, w2.y, acc[m][9]);
                acc[m][10] = fmaf(xs, w2.z, acc[m][10]);
                acc[m][11] = fmaf(xs, w2.w, acc[m][11]);
                acc[m][12] = fmaf(xs, w3.x, acc[m][12]);
                acc[m][13] = fmaf(xs, w3.y, acc[m][13]);
                acc[m][14] = fmaf(xs, w3.z, acc[m][14]);
                acc[m][15] = fmaf(xs, w3.w, acc[m][15]);
                acc[m][16] = fmaf(xs, w4.x, acc[m][16]);
                acc[m][17] = fmaf(xs, w4.y, acc[m][17]);
                acc[m][18] = fmaf(xs, w4.z, acc[m][18]);
                acc[m][19] = fmaf(xs, w4.w, acc[m][19]);
                acc[m][20] = fmaf(xs, w5.x, acc[m][20]);
                acc[m][21] = fmaf(xs, w5.y, acc[m][21]);
                acc[m][22] = fmaf(xs, w5.z, acc[m][22]);
                acc[m][23] = fmaf(xs, w5.w, acc[m][23]);
            }
        }
    }

    const float* bp = b + kf0;
    float bb[24];
    #pragma unroll
    for (int q = 0; q < 24; ++q) bb[q] = bp[q];

    #pragma unroll
    for (int m = 0; m < 4; ++m) {
        float v[24];
        float ssA = 0.f, ssB = 0.f;
        #pragma unroll
        for (int q = 0; q < 12; ++q) {
            v[q] = fmaxf(acc[m][q] + bb[q], 0.f);
            ssA = fmaf(v[q], v[q], ssA);
        }
        #pragma unroll
        for (int q = 12; q < 24; ++q) {
            v[q] = fmaxf(acc[m][q] + bb[q], 0.f);
            ssB = fmaf(v[q], v[q], ssB);
        }
        float invA = rsqrtf(ssA + 1e-12f);
        float invB = rsqrtf(ssB + 1e-12f);
        float* zo = zA + (size_t)(nb + m) * KF + kf0;
        #pragma unroll
        for (int q4 = 0; q4 < 6; ++q4) {
            float sc = (q4 < 3) ? invA : invB;
            float4 t;
            t.x = v[q4*4+0] * sc; t.y = v[q4*4+1] * sc;
            t.z = v[q4*4+2] * sc; t.w = v[q4*4+3] * sc;
            ((float4*)zo)[q4] = t;
        }
    }
}

// ---------- CSR build ----------
__global__ void hist(const int* __restrict__ dst, int* __restrict__ counts) {
    int e = blockIdx.x * 256 + threadIdx.x;
    if (e < M_EDGES) atomicAdd(&counts[dst[e]], 1);
}
__global__ void scan1(const int* __restrict__ counts, int* __restrict__ partial,
                      int* __restrict__ bsums) {
    __shared__ int s[256];
    int t = threadIdx.x;
    int i = blockIdx.x * 256 + t;
    int v = (i < N_NODES) ? counts[i] : 0;
    s[t] = v; __syncthreads();
    for (int off = 1; off < 256; off <<= 1) {
        int tmp = (t >= off) ? s[t - off] : 0;
        __syncthreads();
        s[t] += tmp;
        __syncthreads();
    }
    if (i < N_NODES) partial[i] = s[t];
    if (t == 255) bsums[blockIdx.x] = s[t];
}
__global__ void scan2(int* __restrict__ bs, int nb) {
    __shared__ int s[256];
    int t = threadIdx.x;
    int v = (t < nb) ? bs[t] : 0;
    s[t] = v; __syncthreads();
    for (int off = 1; off < 256; off <<= 1) {
        int tmp = (t >= off) ? s[t - off] : 0;
        __syncthreads();
        s[t] += tmp;
        __syncthreads();
    }
    if (t < nb) bs[t] = s[t] - v;  // exclusive
}
// fused: row_ptr[i+1] = inclusive scan; cursor[i] = row start (= incl - counts[i])
__global__ void finalize_rp(const int* __restrict__ partial, const int* __restrict__ boffs,
                            const int* __restrict__ counts,
                            int* __restrict__ row_ptr, int* __restrict__ cursor) {
    int i = blockIdx.x * 256 + threadIdx.x;
    if (i < N_NODES) {
        int incl = partial[i] + boffs[i >> 8];
        row_ptr[i + 1] = incl;
        cursor[i] = incl - counts[i];
    }
    if (i == 0) row_ptr[0] = 0;
}
__global__ void csr_fill(const int* __restrict__ src, const int* __restrict__ dst,
                         int* __restrict__ cursor, int* __restrict__ csr) {
    int e = blockIdx.x * 256 + threadIdx.x;
    if (e < M_EDGES) {
        int d = dst[e];
        int pos = atomicAdd(&cursor[d], 1);
        csr[pos] = src[e];
    }
}

// ---------- routing layer: TWO nodes per wave, fp16-packed neighbor cache ----------
// lane = h*32 + gp*8 + k : h = node half, gp = edge subgroup (0..3), k = capsule (0..7)
// Neighbor cache zc = half2[6][6] (36 VGPRs vs fp32's 72 -> fits (256,4) cap of 128,
// 4 waves/SIMD, no spill). att via v_dot2_f32_f16 (fp32 accum); agg in fp32 via
// fma_mix; c packed to half2 once per iteration. z,c unit & nonneg => att in [0,1],
// exp never overflows, softmax max-subtraction dropped (shift-invariant).
__global__ __launch_bounds__(256, 4) void route(const float* __restrict__ zin,
                                                float* __restrict__ znext,
                                                float* __restrict__ dout,
                                                const int* __restrict__ row_ptr,
                                                const int* __restrict__ csr,
                                                int write_out) {
    int wid  = (blockIdx.x * 256 + threadIdx.x) >> 6;   // 0..24999
    int lane = threadIdx.x & 63;
    int h  = lane >> 5;        // node within wave
    int gp = (lane >> 3) & 3;  // edge subgroup (4 per node)
    int k  = lane & 7;         // capsule
    int node = wid * 2 + h;    // 25000*2 == N_NODES exactly

    // own z (persistent) and c, fp32
    float z[12], c[12];
    {
        const float4* zr = (const float4*)(zin + (size_t)node * KF + k * FAC);
        #pragma unroll
        for (int q = 0; q < 3; ++q) {
            float4 t = zr[q];
            z[q*4+0]=t.x; z[q*4+1]=t.y; z[q*4+2]=t.z; z[q*4+3]=t.w;
        }
    }
    #pragma unroll
    for (int d = 0; d < 12; ++d) c[d] = z[d];

    int base = row_ptr[node];
    int deg  = row_ptr[node + 1] - base;
    int degc = deg < DMAX ? deg : DMAX;
    int dm = deg;
    dm = max(dm, __shfl_xor(dm, 32));
    bool hasTail = dm > DMAX;

    // ---- one-time gather: 6 slots x 4 edges, packed to half2 ----
    h2 zc[6][6];
    #pragma unroll
    for (int j = 0; j < 6; ++j) {
        int idx = j * 4 + gp;
        if (idx < degc) {
            int s = csr[base + idx];
            const float4* zs4 = (const float4*)(zin + (size_t)s * KF + k * FAC);
            float4 t0 = zs4[0], t1 = zs4[1], t2 = zs4[2];
            zc[j][0] = __builtin_amdgcn_cvt_pkrtz(t0.x, t0.y);
            zc[j][1] = __builtin_amdgcn_cvt_pkrtz(t0.z, t0.w);
            zc[j][2] = __builtin_amdgcn_cvt_pkrtz(t1.x, t1.y);
            zc[j][3] = __builtin_amdgcn_cvt_pkrtz(t1.z, t1.w);
            zc[j][4] = __builtin_amdgcn_cvt_pkrtz(t2.x, t2.y);
            zc[j][5] = __builtin_amdgcn_cvt_pkrtz(t2.z, t2.w);
        } else {
            #pragma unroll
            for (int p = 0; p < 6; ++p) zc[j][p] = (h2)(__fp16)0.f;
        }
    }

    for (int it = 0; it < ROUTIT; ++it) {
        // pack current c once per iteration
        h2 cp[6];
        #pragma unroll
        for (int p = 0; p < 6; ++p)
            cp[p] = __builtin_amdgcn_cvt_pkrtz(c[2*p], c[2*p+1]);

        float agg[12];
        #pragma unroll
        for (int d = 0; d < 12; ++d) agg[d] = 0.f;

        // two phase-major batches of 3 slots (3-wide ILP shuffle chains)
        #pragma unroll
        for (int half = 0; half < 2; ++half) {
            int j0 = half * 3;
            float ex[3], sm[3];
            #pragma unroll
            for (int jj = 0; jj < 3; ++jj) {
                float att = 0.f;
                #pragma unroll
                for (int p = 0; p < 6; ++p) att = FDOT2(zc[j0+jj][p], cp[p], att);
                ex[jj] = __expf(att);      // att in [0,1]: no max needed
                sm[jj] = ex[jj];
            }
            #pragma unroll
            for (int m = 1; m <= 4; m <<= 1) {
                #pragma unroll
                for (int jj = 0; jj < 3; ++jj) sm[jj] += __shfl_xor(sm[jj], m);
            }
            #pragma unroll
            for (int jj = 0; jj < 3; ++jj) {
                float pw = __fdividef(ex[jj], sm[jj]);
                // zc==0 for inactive slots -> contribution auto-zero
                #pragma unroll
                for (int p = 0; p < 6; ++p) {
                    agg[2*p+0] = fmaf(pw, (float)zc[j0+jj][p][0], agg[2*p+0]);
                    agg[2*p+1] = fmaf(pw, (float)zc[j0+jj][p][1], agg[2*p+1]);
                }
            }
        }

        // rare tail: deg > 24 (~2% of nodes) — global re-gather each iteration (fp32)
        if (hasTail) {
            for (int t0 = DMAX; t0 < dm; t0 += 4) {
                int idx = t0 + gp;
                bool act = idx < deg;
                float zs[12];
                #pragma unroll
                for (int d = 0; d < 12; ++d) zs[d] = 0.f;
                if (act) {
                    int s = csr[base + idx];
                    const float4* zs4 = (const float4*)(zin + (size_t)s * KF + k * FAC);
                    #pragma unroll
                    for (int q = 0; q < 3; ++q) {
                        float4 t = zs4[q];
                        zs[q*4+0]=t.x; zs[q*4+1]=t.y; zs[q*4+2]=t.z; zs[q*4+3]=t.w;
                    }
                }
                float att = 0.f;
                #pragma unroll
                for (int d = 0; d < 12; ++d) att = fmaf(zs[d], c[d], att);
                float exv = __expf(att);
                float smv = exv;
                smv += __shfl_xor(smv, 1);
                smv += __shfl_xor(smv, 2);
                smv += __shfl_xor(smv, 4);
                float pw = __fdividef(exv, smv);
                #pragma unroll
                for (int d = 0; d < 12; ++d) agg[d] = fmaf(pw, zs[d], agg[d]);
            }
        }

        // reduce agg over the 4 edge subgroups (stay within the half: masks 8,16)
        #pragma unroll
        for (int d = 0; d < 12; ++d) agg[d] += __shfl_xor(agg[d], 8);
        #pragma unroll
        for (int d = 0; d < 12; ++d) agg[d] += __shfl_xor(agg[d], 16);

        // c = l2norm(z + agg)
        float ss = 0.f;
        float v[12];
        #pragma unroll
        for (int d = 0; d < 12; ++d) { v[d] = z[d] + agg[d]; ss = fmaf(v[d], v[d], ss); }
        float inv = rsqrtf(ss + 1e-12f);
        #pragma unroll
        for (int d = 0; d < 12; ++d) c[d] = v[d] * inv;
    }

    if (gp == 0) {
        float r[12], ss = 0.f;
        #pragma unroll
        for (int d = 0; d < 12; ++d) { r[d] = fmaxf(c[d], 0.f); ss = fmaf(r[d], r[d], ss); }
        if (write_out) {
            // final layer: output is relu(c), un-normalized; znext is dead -> skip it
            float* oo = dout + (size_t)node * KF + k * FAC;
            #pragma unroll
            for (int q = 0; q < 3; ++q) {
                float4 t;
                t.x = r[q*4+0]; t.y = r[q*4+1]; t.z = r[q*4+2]; t.w = r[q*4+3];
                ((float4*)oo)[q] = t;
            }
        } else {
            float inv = rsqrtf(ss + 1e-12f);
            float* zo = znext + (size_t)node * KF + k * FAC;
            #pragma unroll
            for (int q = 0; q < 3; ++q) {
                float4 t;
                t.x = r[q*4+0]*inv; t.y = r[q*4+1]*inv; t.z = r[q*4+2]*inv; t.w = r[q*4+3]*inv;
                ((float4*)zo)[q] = t;
            }
        }
    }
}

extern "C" void kernel_launch(void* const* d_in, const int* in_sizes, int n_in,
                              void* d_out, int out_size, void* d_ws, size_t ws_size,
                              hipStream_t stream) {
    const float* X     = (const float*)d_in[0];
    const int*   edges = (const int*)d_in[1];
    const float* W     = (const float*)d_in[2];
    const float* b     = (const float*)d_in[3];
    float* out = (float*)d_out;
    char* ws = (char*)d_ws;

    float* zA      = (float*)(ws + OFF_ZA);
    float* zB      = (float*)(ws + OFF_ZB);
    int*   row_ptr = (int*)(ws + OFF_ROWPTR);
    int*   partial = (int*)(ws + OFF_PARTIAL);
    int*   cursor  = (int*)(ws + OFF_CURSOR);
    int*   bsums   = (int*)(ws + OFF_BSUMS);
    int*   csr     = (int*)(ws + OFF_CSR);
    float* Wt      = (float*)(ws + OFF_WT);

    const int* src = edges;            // edges[0, :]
    const int* dst = edges + M_EDGES;  // edges[1, :]

    // init projection (fused relu + per-capsule l2norm) -> zA directly
    wt_transpose<<<96, 256, 0, stream>>>(W, Wt);
    init_proj<<<(N_NODES / 4 * 4 + 255) / 256, 256, 0, stream>>>(X, Wt, b, zA);

    // CSR by dst (counts live in `cursor`; finalize_rp converts to row starts)
    (void)hipMemsetAsync(cursor, 0, N_NODES * sizeof(int), stream);
    hist<<<(M_EDGES + 255) / 256, 256, 0, stream>>>(dst, cursor);
    scan1<<<196, 256, 0, stream>>>(cursor, partial, bsums);
    scan2<<<1, 256, 0, stream>>>(bsums, 196);
    finalize_rp<<<196, 256, 0, stream>>>(partial, bsums, cursor, row_ptr, cursor);
    csr_fill<<<(M_EDGES + 255) / 256, 256, 0, stream>>>(src, dst, cursor, csr);

    // 4 routing layers, ping-pong z buffers; last layer writes d_out only
    route<<<6250, 256, 0, stream>>>(zA, zB, nullptr, row_ptr, csr, 0);
    route<<<6250, 256, 0, stream>>>(zB, zA, nullptr, row_ptr, csr, 0);
    route<<<6250, 256, 0, stream>>>(zA, zB, nullptr, row_ptr, csr, 0);
    route<<<6250, 256, 0, stream>>>(zB, zA, out, row_ptr, csr, 1);
}

// Round 15
// 965.647 us; speedup vs baseline: 2.6307x; 2.6307x over previous
//
#include <hip/hip_runtime.h>
#include <math.h>

#define N_NODES 50000
#define M_EDGES 800000
#define INP 256
#define KCAP 8
#define FAC 12
#define KF 96            // K*FAC
#define ROUTIT 6
#define DMAX 24          // register-cached edges per node (6 slots x 4 subgroups)

// NOTE: clang's AMDGPU builtins use __fp16 vectors (BuiltinsAMDGPU.def: cvt_pkrtz
// = "V2hff", fdot2 = "fV2hV2hfb"). _Float16 vectors are a DIFFERENT type and fail
// to compile (round-8 lesson). Use __fp16 throughout.
typedef __fp16 h2 __attribute__((ext_vector_type(2)));

#if __has_builtin(__builtin_amdgcn_fdot2)
#define FDOT2(a, b, c) __builtin_amdgcn_fdot2((a), (b), (c), false)
#else
#define FDOT2(a, b, c) (fmaf((float)(a)[1], (float)(b)[1], fmaf((float)(a)[0], (float)(b)[0], (c))))
#endif

// ---------------- ws layout (bytes) ----------------
#define OFF_ZA      0u
#define OFF_ZB      19200000u
#define OFF_ROWPTR  38400000u   // 50001 ints (padded)
#define OFF_PARTIAL 38600016u   // 50000 ints
#define OFF_CURSOR  38800016u   // 50000 ints (counts -> row starts)
#define OFF_BSUMS   39000016u   // 256 ints
#define OFF_CSR     39001040u   // 800000 ints
#define OFF_WT      42201040u   // 256*96 floats

// ---------- W transpose: Wt[i][kf] = W[k][i][f]  (i-major, kf-minor) ----------
__global__ void wt_transpose(const float* __restrict__ W, float* __restrict__ Wt) {
    int idx = blockIdx.x * 256 + threadIdx.x;
    if (idx >= INP * KF) return;
    int i = idx / KF, kf = idx % KF;
    int k = kf / FAC, f = kf % FAC;
    Wt[i * KF + kf] = W[(k * INP + i) * FAC + f];
}

// ---------- init: zA[n][kf] = l2norm_percap(relu(X[n,:].Wt[:,kf] + b[kf])) ----------
// thread = 4 nodes x 24 kf (2 FULL capsules) -> X row multiplier 24 -> 4 (1.23GB -> 205MB)
// and per-capsule l2norm fuses in-thread (prep_norm kernel deleted).
__global__ __launch_bounds__(256, 2) void init_proj(const float* __restrict__ X,
                                                    const float* __restrict__ Wt,
                                                    const float* __restrict__ b,
                                                    float* __restrict__ zA) {
    int gid    = blockIdx.x * 256 + threadIdx.x;
    int quad   = gid >> 2;      // node quad id
    int pairId = gid & 3;       // capsule pair (2 capsules = 24 kf)
    if (quad >= N_NODES / 4) return;
    int nb  = quad * 4;
    int kf0 = pairId * 24;

    float acc[4][24];
    #pragma unroll
    for (int m = 0; m < 4; ++m)
        #pragma unroll
        for (int q = 0; q < 24; ++q) acc[m][q] = 0.f;

    const float4* X4 = (const float4*)X;

    for (int i4 = 0; i4 < INP / 4; ++i4) {
        float4 xv[4];
        #pragma unroll
        for (int m = 0; m < 4; ++m)
            xv[m] = X4[(size_t)(nb + m) * (INP / 4) + i4];

        #pragma unroll
        for (int r = 0; r < 4; ++r) {
            const float4* wr = (const float4*)(Wt + (size_t)(i4 * 4 + r) * KF + kf0);
            float4 w0 = wr[0], w1 = wr[1], w2 = wr[2], w3 = wr[3], w4 = wr[4], w5 = wr[5];
            #pragma unroll
            for (int m = 0; m < 4; ++m) {
                float xs = (r == 0) ? xv[m].x : (r == 1) ? xv[m].y : (r == 2) ? xv[m].z : xv[m].w;
                acc[m][0]  = fmaf(xs, w0.x, acc[m][0]);
                acc[m][1]  = fmaf(xs, w0.y, acc[m][1]);
                acc[m][2]  = fmaf(xs, w0.z, acc[m][2]);
                acc[m][3]  = fmaf(xs, w0.w, acc[m][3]);
                acc[m][4]  = fmaf(xs, w1.x, acc[m][4]);
                acc[m][5]  = fmaf(xs, w1.y, acc[m][5]);
                acc[m][6]  = fmaf(xs, w1.z, acc[m][6]);
                acc[m][7]  = fmaf(xs, w1.w, acc[m][7]);
                acc[m][8]  = fmaf(xs, w2.x, acc[m][8]);
                acc[m][9]  = fmaf(xs, w2.y, acc[m][9]);
                acc[m][10] = fmaf(xs, w2.z, acc[m][10]);
                acc[m][11] = fmaf(xs, w2.w, acc[m][11]);
                acc[m][12] = fmaf(xs, w3.x, acc[m][12]);
                acc[m][13] = fmaf(xs, w3.y, acc[m][13]);
                acc[m][14] = fmaf(xs, w3.z, acc[m][14]);
                acc[m][15] = fmaf(xs, w3.w, acc[m][15]);
                acc[m][16] = fmaf(xs, w4.x, acc[m][16]);
                acc[m][17] = fmaf(xs, w4.y, acc[m][17]);
                acc[m][18] = fmaf(xs, w4.z, acc[m][18]);
                acc[m][19] = fmaf(xs, w4.w, acc[m][19]);
                acc[m][20] = fmaf(xs, w5.x, acc[m][20]);
                acc[m][21] = fmaf(xs, w5.y, acc[m][21]);
                acc[m][22] = fmaf(xs, w5.z, acc[m][22]);
                acc[m][23] = fmaf(xs, w5.w, acc[m][23]);
            }
        }
    }

    const float* bp = b + kf0;
    float bb[24];
    #pragma unroll
    for (int q = 0; q < 24; ++q) bb[q] = bp[q];

    #pragma unroll
    for (int m = 0; m < 4; ++m) {
        float v[24];
        float ssA = 0.f, ssB = 0.f;
        #pragma unroll
        for (int q = 0; q < 12; ++q) {
            v[q] = fmaxf(acc[m][q] + bb[q], 0.f);
            ssA = fmaf(v[q], v[q], ssA);
        }
        #pragma unroll
        for (int q = 12; q < 24; ++q) {
            v[q] = fmaxf(acc[m][q] + bb[q], 0.f);
            ssB = fmaf(v[q], v[q], ssB);
        }
        float invA = rsqrtf(ssA + 1e-12f);
        float invB = rsqrtf(ssB + 1e-12f);
        float* zo = zA + (size_t)(nb + m) * KF + kf0;
        #pragma unroll
        for (int q4 = 0; q4 < 6; ++q4) {
            float sc = (q4 < 3) ? invA : invB;
            float4 t;
            t.x = v[q4*4+0] * sc; t.y = v[q4*4+1] * sc;
            t.z = v[q4*4+2] * sc; t.w = v[q4*4+3] * sc;
            ((float4*)zo)[q4] = t;
        }
    }
}

// ---------- CSR build ----------
__global__ void hist(const int* __restrict__ dst, int* __restrict__ counts) {
    int e = blockIdx.x * 256 + threadIdx.x;
    if (e < M_EDGES) atomicAdd(&counts[dst[e]], 1);
}
__global__ void scan1(const int* __restrict__ counts, int* __restrict__ partial,
                      int* __restrict__ bsums) {
    __shared__ int s[256];
    int t = threadIdx.x;
    int i = blockIdx.x * 256 + t;
    int v = (i < N_NODES) ? counts[i] : 0;
    s[t] = v; __syncthreads();
    for (int off = 1; off < 256; off <<= 1) {
        int tmp = (t >= off) ? s[t - off] : 0;
        __syncthreads();
        s[t] += tmp;
        __syncthreads();
    }
    if (i < N_NODES) partial[i] = s[t];
    if (t == 255) bsums[blockIdx.x] = s[t];
}
__global__ void scan2(int* __restrict__ bs, int nb) {
    __shared__ int s[256];
    int t = threadIdx.x;
    int v = (t < nb) ? bs[t] : 0;
    s[t] = v; __syncthreads();
    for (int off = 1; off < 256; off <<= 1) {
        int tmp = (t >= off) ? s[t - off] : 0;
        __syncthreads();
        s[t] += tmp;
        __syncthreads();
    }
    if (t < nb) bs[t] = s[t] - v;  // exclusive
}
// fused: row_ptr[i+1] = inclusive scan; cursor[i] = row start (= incl - counts[i])
__global__ void finalize_rp(const int* __restrict__ partial, const int* __restrict__ boffs,
                            const int* __restrict__ counts,
                            int* __restrict__ row_ptr, int* __restrict__ cursor) {
    int i = blockIdx.x * 256 + threadIdx.x;
    if (i < N_NODES) {
        int incl = partial[i] + boffs[i >> 8];
        row_ptr[i + 1] = incl;
        cursor[i] = incl - counts[i];
    }
    if (i == 0) row_ptr[0] = 0;
}
__global__ void csr_fill(const int* __restrict__ src, const int* __restrict__ dst,
                         int* __restrict__ cursor, int* __restrict__ csr) {
    int e = blockIdx.x * 256 + threadIdx.x;
    if (e < M_EDGES) {
        int d = dst[e];
        int pos = atomicAdd(&cursor[d], 1);
        csr[pos] = src[e];
    }
}

// ---------- routing layer: TWO nodes per wave, fp16-packed neighbor cache ----------
// lane = h*32 + gp*8 + k : h = node half, gp = edge subgroup (0..3), k = capsule (0..7)
// launch_bounds(256,3): cap ~170 regs. Round-10 lesson: (256,4)'s cap of 128 made
// the allocator spill the ENTIRE zc cache to scratch (VGPR=64, FETCH 1.13GB, 5x
// slower). Real need is ~130-140; (256,3) fits it in the unified VGPR/AGPR file.
// Occupancy follows ACTUAL allocation: if <=128 regs, HW still runs 4 waves/SIMD.
__global__ __launch_bounds__(256, 3) void route(const float* __restrict__ zin,
                                                float* __restrict__ znext,
                                                float* __restrict__ dout,
                                                const int* __restrict__ row_ptr,
                                                const int* __restrict__ csr,
                                                int write_out) {
    int wid  = (blockIdx.x * 256 + threadIdx.x) >> 6;   // 0..24999
    int lane = threadIdx.x & 63;
    int h  = lane >> 5;        // node within wave
    int gp = (lane >> 3) & 3;  // edge subgroup (4 per node)
    int k  = lane & 7;         // capsule
    int node = wid * 2 + h;    // 25000*2 == N_NODES exactly

    // own z (persistent) and c, fp32
    float z[12], c[12];
    {
        const float4* zr = (const float4*)(zin + (size_t)node * KF + k * FAC);
        #pragma unroll
        for (int q = 0; q < 3; ++q) {
            float4 t = zr[q];
            z[q*4+0]=t.x; z[q*4+1]=t.y; z[q*4+2]=t.z; z[q*4+3]=t.w;
        }
    }
    #pragma unroll
    for (int d = 0; d < 12; ++d) c[d] = z[d];

    int base = row_ptr[node];
    int deg  = row_ptr[node + 1] - base;
    int degc = deg < DMAX ? deg : DMAX;
    int dm = deg;
    dm = max(dm, __shfl_xor(dm, 32));
    bool hasTail = dm > DMAX;

    // ---- one-time gather: 6 slots x 4 edges, packed to half2 ----
    h2 zc[6][6];
    #pragma unroll
    for (int j = 0; j < 6; ++j) {
        int idx = j * 4 + gp;
        if (idx < degc) {
            int s = csr[base + idx];
            const float4* zs4 = (const float4*)(zin + (size_t)s * KF + k * FAC);
            float4 t0 = zs4[0], t1 = zs4[1], t2 = zs4[2];
            zc[j][0] = __builtin_amdgcn_cvt_pkrtz(t0.x, t0.y);
            zc[j][1] = __builtin_amdgcn_cvt_pkrtz(t0.z, t0.w);
            zc[j][2] = __builtin_amdgcn_cvt_pkrtz(t1.x, t1.y);
            zc[j][3] = __builtin_amdgcn_cvt_pkrtz(t1.z, t1.w);
            zc[j][4] = __builtin_amdgcn_cvt_pkrtz(t2.x, t2.y);
            zc[j][5] = __builtin_amdgcn_cvt_pkrtz(t2.z, t2.w);
        } else {
            #pragma unroll
            for (int p = 0; p < 6; ++p) zc[j][p] = (h2)(__fp16)0.f;
        }
    }

    for (int it = 0; it < ROUTIT; ++it) {
        // pack current c once per iteration
        h2 cp[6];
        #pragma unroll
        for (int p = 0; p < 6; ++p)
            cp[p] = __builtin_amdgcn_cvt_pkrtz(c[2*p], c[2*p+1]);

        float agg[12];
        #pragma unroll
        for (int d = 0; d < 12; ++d) agg[d] = 0.f;

        // two phase-major batches of 3 slots (3-wide ILP shuffle chains)
        #pragma unroll
        for (int half = 0; half < 2; ++half) {
            int j0 = half * 3;
            float ex[3], sm[3];
            #pragma unroll
            for (int jj = 0; jj < 3; ++jj) {
                float att = 0.f;
                #pragma unroll
                for (int p = 0; p < 6; ++p) att = FDOT2(zc[j0+jj][p], cp[p], att);
                ex[jj] = __expf(att);      // att in [0,1]: no max needed
                sm[jj] = ex[jj];
            }
            #pragma unroll
            for (int m = 1; m <= 4; m <<= 1) {
                #pragma unroll
                for (int jj = 0; jj < 3; ++jj) sm[jj] += __shfl_xor(sm[jj], m);
            }
            #pragma unroll
            for (int jj = 0; jj < 3; ++jj) {
                float pw = __fdividef(ex[jj], sm[jj]);
                // zc==0 for inactive slots -> contribution auto-zero
                #pragma unroll
                for (int p = 0; p < 6; ++p) {
                    agg[2*p+0] = fmaf(pw, (float)zc[j0+jj][p][0], agg[2*p+0]);
                    agg[2*p+1] = fmaf(pw, (float)zc[j0+jj][p][1], agg[2*p+1]);
                }
            }
        }

        // rare tail: deg > 24 (~2% of nodes) — global re-gather each iteration (fp32)
        if (hasTail) {
            for (int t0 = DMAX; t0 < dm; t0 += 4) {
                int idx = t0 + gp;
                bool act = idx < deg;
                float zs[12];
                #pragma unroll
                for (int d = 0; d < 12; ++d) zs[d] = 0.f;
                if (act) {
                    int s = csr[base + idx];
                    const float4* zs4 = (const float4*)(zin + (size_t)s * KF + k * FAC);
                    #pragma unroll
                    for (int q = 0; q < 3; ++q) {
                        float4 t = zs4[q];
                        zs[q*4+0]=t.x; zs[q*4+1]=t.y; zs[q*4+2]=t.z; zs[q*4+3]=t.w;
                    }
                }
                float att = 0.f;
                #pragma unroll
                for (int d = 0; d < 12; ++d) att = fmaf(zs[d], c[d], att);
                float exv = __expf(att);
                float smv = exv;
                smv += __shfl_xor(smv, 1);
                smv += __shfl_xor(smv, 2);
                smv += __shfl_xor(smv, 4);
                float pw = __fdividef(exv, smv);
                #pragma unroll
                for (int d = 0; d < 12; ++d) agg[d] = fmaf(pw, zs[d], agg[d]);
            }
        }

        // reduce agg over the 4 edge subgroups (stay within the half: masks 8,16)
        #pragma unroll
        for (int d = 0; d < 12; ++d) agg[d] += __shfl_xor(agg[d], 8);
        #pragma unroll
        for (int d = 0; d < 12; ++d) agg[d] += __shfl_xor(agg[d], 16);

        // c = l2norm(z + agg)
        float ss = 0.f;
        float v[12];
        #pragma unroll
        for (int d = 0; d < 12; ++d) { v[d] = z[d] + agg[d]; ss = fmaf(v[d], v[d], ss); }
        float inv = rsqrtf(ss + 1e-12f);
        #pragma unroll
        for (int d = 0; d < 12; ++d) c[d] = v[d] * inv;
    }

    if (gp == 0) {
        float r[12], ss = 0.f;
        #pragma unroll
        for (int d = 0; d < 12; ++d) { r[d] = fmaxf(c[d], 0.f); ss = fmaf(r[d], r[d], ss); }
        if (write_out) {
            // final layer: output is relu(c), un-normalized; znext is dead -> skip it
            float* oo = dout + (size_t)node * KF + k * FAC;
            #pragma unroll
            for (int q = 0; q < 3; ++q) {
                float4 t;
                t.x = r[q*4+0]; t.y = r[q*4+1]; t.z = r[q*4+2]; t.w = r[q*4+3];
                ((float4*)oo)[q] = t;
            }
        } else {
            float inv = rsqrtf(ss + 1e-12f);
            float* zo = znext + (size_t)node * KF + k * FAC;
            #pragma unroll
            for (int q = 0; q < 3; ++q) {
                float4 t;
                t.x = r[q*4+0]*inv; t.y = r[q*4+1]*inv; t.z = r[q*4+2]*inv; t.w = r[q*4+3]*inv;
                ((float4*)zo)[q] = t;
            }
        }
    }
}

extern "C" void kernel_launch(void* const* d_in, const int* in_sizes, int n_in,
                              void* d_out, int out_size, void* d_ws, size_t ws_size,
                              hipStream_t stream) {
    const float* X     = (const float*)d_in[0];
    const int*   edges = (const int*)d_in[1];
    const float* W     = (const float*)d_in[2];
    const float* b     = (const float*)d_in[3];
    float* out = (float*)d_out;
    char* ws = (char*)d_ws;

    float* zA      = (float*)(ws + OFF_ZA);
    float* zB      = (float*)(ws + OFF_ZB);
    int*   row_ptr = (int*)(ws + OFF_ROWPTR);
    int*   partial = (int*)(ws + OFF_PARTIAL);
    int*   cursor  = (int*)(ws + OFF_CURSOR);
    int*   bsums   = (int*)(ws + OFF_BSUMS);
    int*   csr     = (int*)(ws + OFF_CSR);
    float* Wt      = (float*)(ws + OFF_WT);

    const int* src = edges;            // edges[0, :]
    const int* dst = edges + M_EDGES;  // edges[1, :]

    // init projection (fused relu + per-capsule l2norm) -> zA directly
    wt_transpose<<<96, 256, 0, stream>>>(W, Wt);
    init_proj<<<(N_NODES / 4 * 4 + 255) / 256, 256, 0, stream>>>(X, Wt, b, zA);

    // CSR by dst (counts live in `cursor`; finalize_rp converts to row starts)
    (void)hipMemsetAsync(cursor, 0, N_NODES * sizeof(int), stream);
    hist<<<(M_EDGES + 255) / 256, 256, 0, stream>>>(dst, cursor);
    scan1<<<196, 256, 0, stream>>>(cursor, partial, bsums);
    scan2<<<1, 256, 0, stream>>>(bsums, 196);
    finalize_rp<<<196, 256, 0, stream>>>(partial, bsums, cursor, row_ptr, cursor);
    csr_fill<<<(M_EDGES + 255) / 256, 256, 0, stream>>>(src, dst, cursor, csr);

    // 4 routing layers, ping-pong z buffers; last layer writes d_out only
    route<<<6250, 256, 0, stream>>>(zA, zB, nullptr, row_ptr, csr, 0);
    route<<<6250, 256, 0, stream>>>(zB, zA, nullptr, row_ptr, csr, 0);
    route<<<6250, 256, 0, stream>>>(zA, zB, nullptr, row_ptr, csr, 0);
    route<<<6250, 256, 0, stream>>>(zB, zA, out, row_ptr, csr, 1);
}

// Round 16
// 813.866 us; speedup vs baseline: 3.1214x; 1.1865x over previous
//
#include <hip/hip_runtime.h>
#include <math.h>

#define N_NODES 50000
#define M_EDGES 800000
#define INP 256
#define KCAP 8
#define FAC 12
#define KF 96            // K*FAC
#define ROUTIT 6
#define DMAX 24          // register-cached edges per node (6 slots x 4 subgroups)

// ---------------- ws layout (bytes) ----------------
#define OFF_ZA      0u
#define OFF_ZB      19200000u
#define OFF_ROWPTR  38400000u   // 50001 ints (padded)
#define OFF_PARTIAL 38600016u   // 50000 ints
#define OFF_CURSOR  38800016u   // 50000 ints (counts -> row starts)
#define OFF_BSUMS   39000016u   // 256 ints
#define OFF_CSR     39001040u   // 800000 ints
#define OFF_WT      42201040u   // 256*96 floats

// ---------- W transpose: Wt[i][kf] = W[k][i][f]  (i-major, kf-minor) ----------
__global__ void wt_transpose(const float* __restrict__ W, float* __restrict__ Wt) {
    int idx = blockIdx.x * 256 + threadIdx.x;
    if (idx >= INP * KF) return;
    int i = idx / KF, kf = idx % KF;
    int k = kf / FAC, f = kf % FAC;
    Wt[i * KF + kf] = W[(k * INP + i) * FAC + f];
}

// ---------- init: zA[n][kf] = l2norm_percap(relu(X[n,:].Wt[:,kf] + b[kf])) ----------
// ROUND-15 LESSON: 4-node blocking -> only 196 blocks -> 8.9% occupancy, 195us
// latency-bound. Now 1 node x 24 kf (2 FULL capsules, l2norm still fuses): 200k
// threads, 782 blocks (~12 waves/CU). X multiplier unchanged (4 threads/row,
// 205MB L3-resident). ~70 regs, (256,4) cap 128 -> no spill risk.
__global__ __launch_bounds__(256, 4) void init_proj(const float* __restrict__ X,
                                                    const float* __restrict__ Wt,
                                                    const float* __restrict__ b,
                                                    float* __restrict__ zA) {
    int gid    = blockIdx.x * 256 + threadIdx.x;
    int node   = gid >> 2;
    int pairId = gid & 3;       // capsule pair (2 capsules = 24 kf)
    if (node >= N_NODES) return;
    int kf0 = pairId * 24;

    float acc[24];
    #pragma unroll
    for (int q = 0; q < 24; ++q) acc[q] = 0.f;

    const float4* Xr = (const float4*)(X + (size_t)node * INP);

    for (int i4 = 0; i4 < INP / 4; ++i4) {
        float4 xv = Xr[i4];
        #pragma unroll
        for (int r = 0; r < 4; ++r) {
            const float4* wr = (const float4*)(Wt + (size_t)(i4 * 4 + r) * KF + kf0);
            float4 w0 = wr[0], w1 = wr[1], w2 = wr[2], w3 = wr[3], w4 = wr[4], w5 = wr[5];
            float xs = (r == 0) ? xv.x : (r == 1) ? xv.y : (r == 2) ? xv.z : xv.w;
            acc[0]  = fmaf(xs, w0.x, acc[0]);
            acc[1]  = fmaf(xs, w0.y, acc[1]);
            acc[2]  = fmaf(xs, w0.z, acc[2]);
            acc[3]  = fmaf(xs, w0.w, acc[3]);
            acc[4]  = fmaf(xs, w1.x, acc[4]);
            acc[5]  = fmaf(xs, w1.y, acc[5]);
            acc[6]  = fmaf(xs, w1.z, acc[6]);
            acc[7]  = fmaf(xs, w1.w, acc[7]);
            acc[8]  = fmaf(xs, w2.x, acc[8]);
            acc[9]  = fmaf(xs, w2.y, acc[9]);
            acc[10] = fmaf(xs, w2.z, acc[10]);
            acc[11] = fmaf(xs, w2.w, acc[11]);
            acc[12] = fmaf(xs, w3.x, acc[12]);
            acc[13] = fmaf(xs, w3.y, acc[13]);
            acc[14] = fmaf(xs, w3.z, acc[14]);
            acc[15] = fmaf(xs, w3.w, acc[15]);
            acc[16] = fmaf(xs, w4.x, acc[16]);
            acc[17] = fmaf(xs, w4.y, acc[17]);
            acc[18] = fmaf(xs, w4.z, acc[18]);
            acc[19] = fmaf(xs, w4.w, acc[19]);
            acc[20] = fmaf(xs, w5.x, acc[20]);
            acc[21] = fmaf(xs, w5.y, acc[21]);
            acc[22] = fmaf(xs, w5.z, acc[22]);
            acc[23] = fmaf(xs, w5.w, acc[23]);
        }
    }

    const float* bp = b + kf0;
    float v[24];
    float ssA = 0.f, ssB = 0.f;
    #pragma unroll
    for (int q = 0; q < 12; ++q) {
        v[q] = fmaxf(acc[q] + bp[q], 0.f);
        ssA = fmaf(v[q], v[q], ssA);
    }
    #pragma unroll
    for (int q = 12; q < 24; ++q) {
        v[q] = fmaxf(acc[q] + bp[q], 0.f);
        ssB = fmaf(v[q], v[q], ssB);
    }
    float invA = rsqrtf(ssA + 1e-12f);
    float invB = rsqrtf(ssB + 1e-12f);
    float* zo = zA + (size_t)node * KF + kf0;
    #pragma unroll
    for (int q4 = 0; q4 < 6; ++q4) {
        float sc = (q4 < 3) ? invA : invB;
        float4 t;
        t.x = v[q4*4+0] * sc; t.y = v[q4*4+1] * sc;
        t.z = v[q4*4+2] * sc; t.w = v[q4*4+3] * sc;
        ((float4*)zo)[q4] = t;
    }
}

// ---------- CSR build ----------
__global__ void hist(const int* __restrict__ dst, int* __restrict__ counts) {
    int e = blockIdx.x * 256 + threadIdx.x;
    if (e < M_EDGES) atomicAdd(&counts[dst[e]], 1);
}
__global__ void scan1(const int* __restrict__ counts, int* __restrict__ partial,
                      int* __restrict__ bsums) {
    __shared__ int s[256];
    int t = threadIdx.x;
    int i = blockIdx.x * 256 + t;
    int v = (i < N_NODES) ? counts[i] : 0;
    s[t] = v; __syncthreads();
    for (int off = 1; off < 256; off <<= 1) {
        int tmp = (t >= off) ? s[t - off] : 0;
        __syncthreads();
        s[t] += tmp;
        __syncthreads();
    }
    if (i < N_NODES) partial[i] = s[t];
    if (t == 255) bsums[blockIdx.x] = s[t];
}
__global__ void scan2(int* __restrict__ bs, int nb) {
    __shared__ int s[256];
    int t = threadIdx.x;
    int v = (t < nb) ? bs[t] : 0;
    s[t] = v; __syncthreads();
    for (int off = 1; off < 256; off <<= 1) {
        int tmp = (t >= off) ? s[t - off] : 0;
        __syncthreads();
        s[t] += tmp;
        __syncthreads();
    }
    if (t < nb) bs[t] = s[t] - v;  // exclusive
}
// fused: row_ptr[i+1] = inclusive scan; cursor[i] = row start (= incl - counts[i])
__global__ void finalize_rp(const int* __restrict__ partial, const int* __restrict__ boffs,
                            const int* __restrict__ counts,
                            int* __restrict__ row_ptr, int* __restrict__ cursor) {
    int i = blockIdx.x * 256 + threadIdx.x;
    if (i < N_NODES) {
        int incl = partial[i] + boffs[i >> 8];
        row_ptr[i + 1] = incl;
        cursor[i] = incl - counts[i];
    }
    if (i == 0) row_ptr[0] = 0;
}
__global__ void csr_fill(const int* __restrict__ src, const int* __restrict__ dst,
                         int* __restrict__ cursor, int* __restrict__ csr) {
    int e = blockIdx.x * 256 + threadIdx.x;
    if (e < M_EDGES) {
        int d = dst[e];
        int pos = atomicAdd(&cursor[d], 1);
        csr[pos] = src[e];
    }
}

// ---------- routing layer: TWO nodes per wave, fp32 neighbor cache ----------
// REVERTED to the round-5 HW-measured config (113.8us, absmax 2e-3, no spill).
// Round-15 showed the fp16-packed cache variant runs ~165-175us at the same
// bounds: the (float)h2 converts in the agg FMAs add ~25% VALU instructions
// (cvt not fused to fma_mix), swamping the fdot2 saving. fp32 zc[6][12] +
// launch_bounds(256,3) (cap ~170; (256,4)'s 128 spills -- round-4/10 lesson).
__global__ __launch_bounds__(256, 3) void route(const float* __restrict__ zin,
                                                float* __restrict__ znext,
                                                float* __restrict__ dout,
                                                const int* __restrict__ row_ptr,
                                                const int* __restrict__ csr,
                                                int write_out) {
    int wid  = (blockIdx.x * 256 + threadIdx.x) >> 6;   // 0..24999
    int lane = threadIdx.x & 63;
    int h  = lane >> 5;        // node within wave
    int gp = (lane >> 3) & 3;  // edge subgroup (4 per node)
    int k  = lane & 7;         // capsule
    int node = wid * 2 + h;    // 25000*2 == N_NODES exactly

    // own z (persistent) and c
    float z[12], c[12];
    {
        const float4* zr = (const float4*)(zin + (size_t)node * KF + k * FAC);
        #pragma unroll
        for (int q = 0; q < 3; ++q) {
            float4 t = zr[q];
            z[q*4+0]=t.x; z[q*4+1]=t.y; z[q*4+2]=t.z; z[q*4+3]=t.w;
        }
    }
    #pragma unroll
    for (int d = 0; d < 12; ++d) c[d] = z[d];

    int base = row_ptr[node];
    int deg  = row_ptr[node + 1] - base;
    int degc = deg < DMAX ? deg : DMAX;
    int dm = deg;
    dm = max(dm, __shfl_xor(dm, 32));
    bool hasTail = dm > DMAX;

    // ---- one-time gather: 6 slots x 4 edges ----
    float zc[6][12];
    #pragma unroll
    for (int j = 0; j < 6; ++j) {
        int idx = j * 4 + gp;
        if (idx < degc) {
            int s = csr[base + idx];
            const float4* zs4 = (const float4*)(zin + (size_t)s * KF + k * FAC);
            #pragma unroll
            for (int q = 0; q < 3; ++q) {
                float4 t = zs4[q];
                zc[j][q*4+0]=t.x; zc[j][q*4+1]=t.y; zc[j][q*4+2]=t.z; zc[j][q*4+3]=t.w;
            }
        } else {
            #pragma unroll
            for (int d = 0; d < 12; ++d) zc[j][d] = 0.f;
        }
    }

    for (int it = 0; it < ROUTIT; ++it) {
        float agg[12];
        #pragma unroll
        for (int d = 0; d < 12; ++d) agg[d] = 0.f;

        // two phase-major batches of 3 slots each (3-wide ILP shuffle chains)
        #pragma unroll
        for (int half = 0; half < 2; ++half) {
            int j0 = half * 3;
            float ex[3], sm[3];
            #pragma unroll
            for (int jj = 0; jj < 3; ++jj) {
                float att = 0.f;
                #pragma unroll
                for (int d = 0; d < 12; ++d) att = fmaf(zc[j0+jj][d], c[d], att);
                ex[jj] = __expf(att);      // att in [0,1]: no max needed
                sm[jj] = ex[jj];
            }
            #pragma unroll
            for (int m = 1; m <= 4; m <<= 1) {
                #pragma unroll
                for (int jj = 0; jj < 3; ++jj) sm[jj] += __shfl_xor(sm[jj], m);
            }
            #pragma unroll
            for (int jj = 0; jj < 3; ++jj) {
                float p = __fdividef(ex[jj], sm[jj]);
                // zc==0 for inactive slots -> contribution auto-zero
                #pragma unroll
                for (int d = 0; d < 12; ++d) agg[d] = fmaf(p, zc[j0+jj][d], agg[d]);
            }
        }

        // rare tail: deg > 24 (~2% of nodes) — global re-gather each iteration
        if (hasTail) {
            for (int t0 = DMAX; t0 < dm; t0 += 4) {
                int idx = t0 + gp;
                bool act = idx < deg;
                float zs[12];
                #pragma unroll
                for (int d = 0; d < 12; ++d) zs[d] = 0.f;
                if (act) {
                    int s = csr[base + idx];
                    const float4* zs4 = (const float4*)(zin + (size_t)s * KF + k * FAC);
                    #pragma unroll
                    for (int q = 0; q < 3; ++q) {
                        float4 t = zs4[q];
                        zs[q*4+0]=t.x; zs[q*4+1]=t.y; zs[q*4+2]=t.z; zs[q*4+3]=t.w;
                    }
                }
                float att = 0.f;
                #pragma unroll
                for (int d = 0; d < 12; ++d) att = fmaf(zs[d], c[d], att);
                float exv = __expf(att);
                float smv = exv;
                smv += __shfl_xor(smv, 1);
                smv += __shfl_xor(smv, 2);
                smv += __shfl_xor(smv, 4);
                float p = __fdividef(exv, smv);
                #pragma unroll
                for (int d = 0; d < 12; ++d) agg[d] = fmaf(p, zs[d], agg[d]);
            }
        }

        // reduce agg over the 4 edge subgroups (stay within the half: masks 8,16)
        #pragma unroll
        for (int d = 0; d < 12; ++d) agg[d] += __shfl_xor(agg[d], 8);
        #pragma unroll
        for (int d = 0; d < 12; ++d) agg[d] += __shfl_xor(agg[d], 16);

        // c = l2norm(z + agg)
        float ss = 0.f;
        float v[12];
        #pragma unroll
        for (int d = 0; d < 12; ++d) { v[d] = z[d] + agg[d]; ss = fmaf(v[d], v[d], ss); }
        float inv = rsqrtf(ss + 1e-12f);
        #pragma unroll
        for (int d = 0; d < 12; ++d) c[d] = v[d] * inv;
    }

    if (gp == 0) {
        float r[12], ss = 0.f;
        #pragma unroll
        for (int d = 0; d < 12; ++d) { r[d] = fmaxf(c[d], 0.f); ss = fmaf(r[d], r[d], ss); }
        if (write_out) {
            // final layer: output is relu(c), un-normalized; znext is dead -> skip it
            float* oo = dout + (size_t)node * KF + k * FAC;
            #pragma unroll
            for (int q = 0; q < 3; ++q) {
                float4 t;
                t.x = r[q*4+0]; t.y = r[q*4+1]; t.z = r[q*4+2]; t.w = r[q*4+3];
                ((float4*)oo)[q] = t;
            }
        } else {
            float inv = rsqrtf(ss + 1e-12f);
            float* zo = znext + (size_t)node * KF + k * FAC;
            #pragma unroll
            for (int q = 0; q < 3; ++q) {
                float4 t;
                t.x = r[q*4+0]*inv; t.y = r[q*4+1]*inv; t.z = r[q*4+2]*inv; t.w = r[q*4+3]*inv;
                ((float4*)zo)[q] = t;
            }
        }
    }
}

extern "C" void kernel_launch(void* const* d_in, const int* in_sizes, int n_in,
                              void* d_out, int out_size, void* d_ws, size_t ws_size,
                              hipStream_t stream) {
    const float* X     = (const float*)d_in[0];
    const int*   edges = (const int*)d_in[1];
    const float* W     = (const float*)d_in[2];
    const float* b     = (const float*)d_in[3];
    float* out = (float*)d_out;
    char* ws = (char*)d_ws;

    float* zA      = (float*)(ws + OFF_ZA);
    float* zB      = (float*)(ws + OFF_ZB);
    int*   row_ptr = (int*)(ws + OFF_ROWPTR);
    int*   partial = (int*)(ws + OFF_PARTIAL);
    int*   cursor  = (int*)(ws + OFF_CURSOR);
    int*   bsums   = (int*)(ws + OFF_BSUMS);
    int*   csr     = (int*)(ws + OFF_CSR);
    float* Wt      = (float*)(ws + OFF_WT);

    const int* src = edges;            // edges[0, :]
    const int* dst = edges + M_EDGES;  // edges[1, :]

    // init projection (fused relu + per-capsule l2norm) -> zA directly
    wt_transpose<<<96, 256, 0, stream>>>(W, Wt);
    init_proj<<<(N_NODES * 4 + 255) / 256, 256, 0, stream>>>(X, Wt, b, zA);

    // CSR by dst (counts live in `cursor`; finalize_rp converts to row starts)
    (void)hipMemsetAsync(cursor, 0, N_NODES * sizeof(int), stream);
    hist<<<(M_EDGES + 255) / 256, 256, 0, stream>>>(dst, cursor);
    scan1<<<196, 256, 0, stream>>>(cursor, partial, bsums);
    scan2<<<1, 256, 0, stream>>>(bsums, 196);
    finalize_rp<<<196, 256, 0, stream>>>(partial, bsums, cursor, row_ptr, cursor);
    csr_fill<<<(M_EDGES + 255) / 256, 256, 0, stream>>>(src, dst, cursor, csr);

    // 4 routing layers, ping-pong z buffers; last layer writes d_out only
    route<<<6250, 256, 0, stream>>>(zA, zB, nullptr, row_ptr, csr, 0);
    route<<<6250, 256, 0, stream>>>(zB, zA, nullptr, row_ptr, csr, 0);
    route<<<6250, 256, 0, stream>>>(zA, zB, nullptr, row_ptr, csr, 0);
    route<<<6250, 256, 0, stream>>>(zB, zA, out, row_ptr, csr, 1);
}